// Round 1
// baseline (749.904 us; speedup 1.0000x reference)
//
#include <hip/hip_runtime.h>
#include <stdint.h>

typedef float f32x4 __attribute__((ext_vector_type(4)));
typedef short bf16x8 __attribute__((ext_vector_type(8)));

constexpr int NB = 4;      // batch
constexpr int NS = 2048;   // sequence
constexpr int ND = 512;    // model dim
constexpr int NH = 8;      // heads
constexpr int NDK = 64;    // head dim
constexpr float NEGINF = -1e30f;

static __device__ __forceinline__ unsigned short f2bf(float f) {
    union { float f; uint32_t u; } v; v.f = f;
    uint32_t r = (v.u + 0x7FFFu + ((v.u >> 16) & 1u)) >> 16;
    return (unsigned short)r;
}

// ---------------- fp32 -> bf16 convert ----------------
__global__ __launch_bounds__(256) void cvt_bf16_kernel(const float4* __restrict__ in,
                                                       ushort4* __restrict__ out, int n4) {
    int i = blockIdx.x * blockDim.x + threadIdx.x;
    if (i >= n4) return;
    float4 v = in[i];
    ushort4 o;
    o.x = f2bf(v.x); o.y = f2bf(v.y); o.z = f2bf(v.z); o.w = f2bf(v.w);
    out[i] = o;
}

// ---------------- projection: Y = X @ W^T + b (then scale) ----------------
// X: [NB*NS][ND] bf16, W: [ND][ND] bf16 (row = output feature), bias fp32.
// vtrans==0: out[(b*NH+h)*NS + s)*NDK + d]   (Q,K layout)
// vtrans==1: out[(b*NH+h)*NDK + d)*NS + s]   (V transposed layout)
__global__ __launch_bounds__(256) void proj_kernel(const unsigned short* __restrict__ X,
                                                   const unsigned short* __restrict__ W,
                                                   const float* __restrict__ bias,
                                                   unsigned short* __restrict__ out,
                                                   float scale, int vtrans) {
    int lane = threadIdx.x & 63;
    int wave = threadIdx.x >> 6;
    int lrow = lane & 15, lgrp = lane >> 4;
    int m0 = blockIdx.x * 64 + wave * 16;
    int n0 = blockIdx.y * 64;

    f32x4 acc[4] = {{0.f,0.f,0.f,0.f},{0.f,0.f,0.f,0.f},{0.f,0.f,0.f,0.f},{0.f,0.f,0.f,0.f}};
    const unsigned short* xrow = X + (size_t)(m0 + lrow) * ND;
    for (int k = 0; k < ND; k += 32) {
        bf16x8 a = *(const bf16x8*)(xrow + k + lgrp * 8);
#pragma unroll
        for (int n = 0; n < 4; n++) {
            bf16x8 b = *(const bf16x8*)(W + (size_t)(n0 + n * 16 + lrow) * ND + k + lgrp * 8);
            acc[n] = __builtin_amdgcn_mfma_f32_16x16x32_bf16(a, b, acc[n], 0, 0, 0);
        }
    }
#pragma unroll
    for (int n = 0; n < 4; n++) {
        int col = n0 + n * 16 + lrow;   // output feature = h*64 + d
        int h = col >> 6, d = col & 63;
        float bv = bias[col];
#pragma unroll
        for (int j = 0; j < 4; j++) {
            int m = m0 + lgrp * 4 + j;
            int bidx = m >> 11, s = m & (NS - 1);
            float y = (acc[n][j] + bv) * scale;
            size_t off = vtrans ? ((size_t)(bidx * NH + h) * NDK + d) * NS + s
                                : ((size_t)(bidx * NH + h) * NS + s) * NDK + d;
            out[off] = f2bf(y);
        }
    }
}

// ---------------- attention ----------------
// Q,K: [NB*NH][NS][NDK] bf16 (Q pre-scaled by 1/8), VT: [NB*NH][NDK][NS] bf16.
// mask int32 [NB][NS][NS] (nonzero -> masked).
// attn_out fp32 [NB*NH][NS][NS]; Ob fp32 [NB][NS][ND].
__global__ __launch_bounds__(256) void attn_kernel(const unsigned short* __restrict__ Q,
                                                   const unsigned short* __restrict__ K,
                                                   const unsigned short* __restrict__ VT,
                                                   const int* __restrict__ mask,
                                                   float* __restrict__ attn_out,
                                                   float* __restrict__ Ob) {
    __shared__ __align__(16) unsigned short pl[4][16][72];  // per-wave P tile, padded rows
    int lane = threadIdx.x & 63;
    int wave = threadIdx.x >> 6;
    int lrow = lane & 15, lgrp = lane >> 4;
    int bh = blockIdx.y;
    int b = bh >> 3, h = bh & 7;
    int qw = blockIdx.x * 64 + wave * 16;   // this wave's 16 q rows

    const unsigned short* qrow = Q + ((size_t)bh * NS + qw + lrow) * NDK + lgrp * 8;
    bf16x8 aq0 = *(const bf16x8*)(qrow);
    bf16x8 aq1 = *(const bf16x8*)(qrow + 32);

    const int* mbase = mask + (size_t)b * NS * NS;
    const unsigned short* kbase = K + (size_t)bh * NS * NDK;
    const unsigned short* vbase = VT + (size_t)bh * NDK * NS;

    float mrun[4] = {NEGINF, NEGINF, NEGINF, NEGINF};
    float lrun[4] = {0.f, 0.f, 0.f, 0.f};

    // -------- sweep 1: running row max + sum of exp --------
    for (int kt = 0; kt < NS; kt += 64) {
        f32x4 sc[4] = {{0.f,0.f,0.f,0.f},{0.f,0.f,0.f,0.f},{0.f,0.f,0.f,0.f},{0.f,0.f,0.f,0.f}};
#pragma unroll
        for (int n = 0; n < 4; n++) {
            const unsigned short* krow = kbase + (size_t)(kt + n * 16 + lrow) * NDK + lgrp * 8;
            bf16x8 b0 = *(const bf16x8*)(krow);
            bf16x8 b1 = *(const bf16x8*)(krow + 32);
            sc[n] = __builtin_amdgcn_mfma_f32_16x16x32_bf16(aq0, b0, sc[n], 0, 0, 0);
            sc[n] = __builtin_amdgcn_mfma_f32_16x16x32_bf16(aq1, b1, sc[n], 0, 0, 0);
        }
        float sv[4][4];
#pragma unroll
        for (int n = 0; n < 4; n++)
#pragma unroll
            for (int j = 0; j < 4; j++) {
                int qi = qw + lgrp * 4 + j;
                int ki = kt + n * 16 + lrow;
                sv[n][j] = mbase[(size_t)qi * NS + ki] ? NEGINF : sc[n][j];
            }
#pragma unroll
        for (int j = 0; j < 4; j++) {
            float tm = fmaxf(fmaxf(sv[0][j], sv[1][j]), fmaxf(sv[2][j], sv[3][j]));
            tm = fmaxf(tm, __shfl_xor(tm, 1));
            tm = fmaxf(tm, __shfl_xor(tm, 2));
            tm = fmaxf(tm, __shfl_xor(tm, 4));
            tm = fmaxf(tm, __shfl_xor(tm, 8));
            float mnew = fmaxf(mrun[j], tm);
            float su = __expf(sv[0][j] - mnew) + __expf(sv[1][j] - mnew)
                     + __expf(sv[2][j] - mnew) + __expf(sv[3][j] - mnew);
            su += __shfl_xor(su, 1);
            su += __shfl_xor(su, 2);
            su += __shfl_xor(su, 4);
            su += __shfl_xor(su, 8);
            lrun[j] = lrun[j] * __expf(mrun[j] - mnew) + su;
            mrun[j] = mnew;
        }
    }
    float invl[4];
#pragma unroll
    for (int j = 0; j < 4; j++) invl[j] = 1.f / lrun[j];

    // -------- sweep 2: recompute scores, write attn, accumulate O = P @ V --------
    f32x4 accO[4] = {{0.f,0.f,0.f,0.f},{0.f,0.f,0.f,0.f},{0.f,0.f,0.f,0.f},{0.f,0.f,0.f,0.f}};
    float* aout = attn_out + (size_t)bh * NS * NS;
    for (int kt = 0; kt < NS; kt += 64) {
        f32x4 sc[4] = {{0.f,0.f,0.f,0.f},{0.f,0.f,0.f,0.f},{0.f,0.f,0.f,0.f},{0.f,0.f,0.f,0.f}};
#pragma unroll
        for (int n = 0; n < 4; n++) {
            const unsigned short* krow = kbase + (size_t)(kt + n * 16 + lrow) * NDK + lgrp * 8;
            bf16x8 b0 = *(const bf16x8*)(krow);
            bf16x8 b1 = *(const bf16x8*)(krow + 32);
            sc[n] = __builtin_amdgcn_mfma_f32_16x16x32_bf16(aq0, b0, sc[n], 0, 0, 0);
            sc[n] = __builtin_amdgcn_mfma_f32_16x16x32_bf16(aq1, b1, sc[n], 0, 0, 0);
        }
#pragma unroll
        for (int n = 0; n < 4; n++)
#pragma unroll
            for (int j = 0; j < 4; j++) {
                int qi = qw + lgrp * 4 + j;
                int ki = kt + n * 16 + lrow;
                float p = mbase[(size_t)qi * NS + ki] ? 0.f
                        : __expf(sc[n][j] - mrun[j]) * invl[j];
                aout[(size_t)qi * NS + ki] = p;
                pl[wave][lgrp * 4 + j][n * 16 + lrow] = f2bf(p);
            }
#pragma unroll
        for (int step = 0; step < 2; step++) {
            bf16x8 ap = *(const bf16x8*)&pl[wave][lrow][step * 32 + lgrp * 8];
#pragma unroll
            for (int n = 0; n < 4; n++) {
                const unsigned short* vrow = vbase + (size_t)(n * 16 + lrow) * NS + kt + step * 32 + lgrp * 8;
                bf16x8 bv = *(const bf16x8*)vrow;
                accO[n] = __builtin_amdgcn_mfma_f32_16x16x32_bf16(ap, bv, accO[n], 0, 0, 0);
            }
        }
    }
#pragma unroll
    for (int n = 0; n < 4; n++)
#pragma unroll
        for (int j = 0; j < 4; j++) {
            int qi = qw + lgrp * 4 + j;
            Ob[((size_t)b * NS + qi) * ND + h * NDK + n * 16 + lrow] = accO[n][j];
        }
}

// ---------------- residual + LayerNorm (OpenNMT: unbiased std, eps on std) ----------------
__global__ __launch_bounds__(256) void ln_kernel(const float* __restrict__ Ob,
                                                 const float* __restrict__ query,
                                                 const float* __restrict__ a2,
                                                 const float* __restrict__ b2,
                                                 float* __restrict__ out) {
    int row = blockIdx.x * 4 + (threadIdx.x >> 6);
    int lane = threadIdx.x & 63;
    const float4* orow = (const float4*)(Ob + (size_t)row * ND);
    const float4* qrow = (const float4*)(query + (size_t)row * ND);
    float4 v[2];
    float sum = 0.f;
#pragma unroll
    for (int t = 0; t < 2; t++) {
        float4 o = orow[lane + t * 64];
        float4 q = qrow[lane + t * 64];
        v[t].x = o.x + q.x; v[t].y = o.y + q.y; v[t].z = o.z + q.z; v[t].w = o.w + q.w;
        sum += v[t].x + v[t].y + v[t].z + v[t].w;
    }
#pragma unroll
    for (int s = 1; s < 64; s <<= 1) sum += __shfl_xor(sum, s);
    float mu = sum * (1.f / ND);
    float sq = 0.f;
#pragma unroll
    for (int t = 0; t < 2; t++) {
        float dx = v[t].x - mu, dy = v[t].y - mu, dz = v[t].z - mu, dw = v[t].w - mu;
        sq += dx * dx + dy * dy + dz * dz + dw * dw;
    }
#pragma unroll
    for (int s = 1; s < 64; s <<= 1) sq += __shfl_xor(sq, s);
    float var = sq * (1.f / (ND - 1));
    float inv = 1.f / (sqrtf(var) + 1e-6f);
    float4* orow_out = (float4*)(out + (size_t)row * ND);
#pragma unroll
    for (int t = 0; t < 2; t++) {
        float4 g = ((const float4*)a2)[lane + t * 64];
        float4 bb = ((const float4*)b2)[lane + t * 64];
        float4 r;
        r.x = g.x * (v[t].x - mu) * inv + bb.x;
        r.y = g.y * (v[t].y - mu) * inv + bb.y;
        r.z = g.z * (v[t].z - mu) * inv + bb.z;
        r.w = g.w * (v[t].w - mu) * inv + bb.w;
        orow_out[lane + t * 64] = r;
    }
}

extern "C" void kernel_launch(void* const* d_in, const int* in_sizes, int n_in,
                              void* d_out, int out_size, void* d_ws, size_t ws_size,
                              hipStream_t stream) {
    const float* key   = (const float*)d_in[0];
    const float* value = (const float*)d_in[1];
    const float* query = (const float*)d_in[2];
    const int*   mask  = (const int*)d_in[3];
    const float* Wk = (const float*)d_in[4];
    const float* bk = (const float*)d_in[5];
    const float* Wv = (const float*)d_in[6];
    const float* bv = (const float*)d_in[7];
    const float* Wq = (const float*)d_in[8];
    const float* bq = (const float*)d_in[9];
    const float* a2 = (const float*)d_in[10];
    const float* b2 = (const float*)d_in[11];

    const size_t nX = (size_t)NB * NS * ND;   // 4,194,304
    const size_t nW = (size_t)ND * ND;        // 262,144

    unsigned short* xq  = (unsigned short*)d_ws;  // bf16 buffers
    unsigned short* xk  = xq + nX;
    unsigned short* xv  = xk + nX;
    unsigned short* wqb = xv + nX;
    unsigned short* wkb = wqb + nW;
    unsigned short* wvb = wkb + nW;
    unsigned short* Qw  = wvb + nW;               // [BH][S][dk]
    unsigned short* Kw  = Qw + nX;                // [BH][S][dk]
    unsigned short* VTw = Kw + nX;                // [BH][dk][S]
    float* Ow = (float*)(VTw + nX);               // [B][S][D] fp32

    cvt_bf16_kernel<<<(int)(nX / 4 / 256), 256, 0, stream>>>((const float4*)query, (ushort4*)xq, (int)(nX / 4));
    cvt_bf16_kernel<<<(int)(nX / 4 / 256), 256, 0, stream>>>((const float4*)key,   (ushort4*)xk, (int)(nX / 4));
    cvt_bf16_kernel<<<(int)(nX / 4 / 256), 256, 0, stream>>>((const float4*)value, (ushort4*)xv, (int)(nX / 4));
    cvt_bf16_kernel<<<(int)(nW / 4 / 256), 256, 0, stream>>>((const float4*)Wq, (ushort4*)wqb, (int)(nW / 4));
    cvt_bf16_kernel<<<(int)(nW / 4 / 256), 256, 0, stream>>>((const float4*)Wk, (ushort4*)wkb, (int)(nW / 4));
    cvt_bf16_kernel<<<(int)(nW / 4 / 256), 256, 0, stream>>>((const float4*)Wv, (ushort4*)wvb, (int)(nW / 4));

    dim3 pg(128, 8);
    proj_kernel<<<pg, 256, 0, stream>>>(xq, wqb, bq, Qw, 0.125f, 0);  // Q scaled by 1/sqrt(dk)
    proj_kernel<<<pg, 256, 0, stream>>>(xk, wkb, bk, Kw, 1.0f, 0);
    proj_kernel<<<pg, 256, 0, stream>>>(xv, wvb, bv, VTw, 1.0f, 1);

    float* attn_out = (float*)d_out + nX;  // res occupies first nX floats
    attn_kernel<<<dim3(32, 32), 256, 0, stream>>>(Qw, Kw, VTw, mask, attn_out, Ow);

    ln_kernel<<<2048, 256, 0, stream>>>(Ow, query, a2, b2, (float*)d_out);
}

// Round 2
// 556.019 us; speedup vs baseline: 1.3487x; 1.3487x over previous
//
#include <hip/hip_runtime.h>
#include <stdint.h>

typedef float f32x4 __attribute__((ext_vector_type(4)));
typedef short bf16x8 __attribute__((ext_vector_type(8)));

constexpr int NB = 4;      // batch
constexpr int NS = 2048;   // sequence
constexpr int ND = 512;    // model dim
constexpr int NH = 8;      // heads
constexpr int NDK = 64;    // head dim
constexpr float NEGINF = -1e30f;

static __device__ __forceinline__ unsigned short f2bf(float f) {
    union { float f; uint32_t u; } v; v.f = f;
    uint32_t r = (v.u + 0x7FFFu + ((v.u >> 16) & 1u)) >> 16;
    return (unsigned short)r;
}

// ---------------- fp32 -> bf16 convert ----------------
__global__ __launch_bounds__(256) void cvt_bf16_kernel(const float4* __restrict__ in,
                                                       ushort4* __restrict__ out, int n4) {
    int i = blockIdx.x * blockDim.x + threadIdx.x;
    if (i >= n4) return;
    float4 v = in[i];
    ushort4 o;
    o.x = f2bf(v.x); o.y = f2bf(v.y); o.z = f2bf(v.z); o.w = f2bf(v.w);
    out[i] = o;
}

// ---------------- mask int32 -> bitmask (1 bit per element) ----------------
// bm word w covers elements [w*64, w*64+64); bit i = (mask[w*64+i] != 0)
__global__ __launch_bounds__(256) void bitmask_kernel(const int* __restrict__ mask,
                                                      unsigned long long* __restrict__ bm,
                                                      int nwords) {
    int lane = threadIdx.x & 63;
    int wave = threadIdx.x >> 6;
    int wgid = blockIdx.x * 4 + wave;
    int nw = gridDim.x * 4;
    for (int c = wgid; c < nwords; c += nw) {
        int v = mask[(size_t)c * 64 + lane];
        unsigned long long bits = __ballot(v != 0);
        if (lane == 0) bm[c] = bits;
    }
}

// ---------------- projection: Y = X @ W^T + b (then scale) ----------------
__global__ __launch_bounds__(256) void proj_kernel(const unsigned short* __restrict__ X,
                                                   const unsigned short* __restrict__ W,
                                                   const float* __restrict__ bias,
                                                   unsigned short* __restrict__ out,
                                                   float scale, int vtrans) {
    int lane = threadIdx.x & 63;
    int wave = threadIdx.x >> 6;
    int lrow = lane & 15, lgrp = lane >> 4;
    int m0 = blockIdx.x * 64 + wave * 16;
    int n0 = blockIdx.y * 64;

    f32x4 acc[4] = {{0.f,0.f,0.f,0.f},{0.f,0.f,0.f,0.f},{0.f,0.f,0.f,0.f},{0.f,0.f,0.f,0.f}};
    const unsigned short* xrow = X + (size_t)(m0 + lrow) * ND;
    for (int k = 0; k < ND; k += 32) {
        bf16x8 a = *(const bf16x8*)(xrow + k + lgrp * 8);
#pragma unroll
        for (int n = 0; n < 4; n++) {
            bf16x8 b = *(const bf16x8*)(W + (size_t)(n0 + n * 16 + lrow) * ND + k + lgrp * 8);
            acc[n] = __builtin_amdgcn_mfma_f32_16x16x32_bf16(a, b, acc[n], 0, 0, 0);
        }
    }
#pragma unroll
    for (int n = 0; n < 4; n++) {
        int col = n0 + n * 16 + lrow;   // output feature = h*64 + d
        int h = col >> 6, d = col & 63;
        float bv = bias[col];
#pragma unroll
        for (int j = 0; j < 4; j++) {
            int m = m0 + lgrp * 4 + j;
            int bidx = m >> 11, s = m & (NS - 1);
            float y = (acc[n][j] + bv) * scale;
            size_t off = vtrans ? ((size_t)(bidx * NH + h) * NDK + d) * NS + s
                                : ((size_t)(bidx * NH + h) * NS + s) * NDK + d;
            out[off] = f2bf(y);
        }
    }
}

// ---------------- attention ----------------
// 512 threads = 8 waves. wave = (kh<<2)|wgrp: wgrp picks 16 q-rows, kh picks K-half.
// Q,K: [BH][S][dk] bf16 (Q pre-scaled), VT: [BH][dk][S] bf16, bm: [B][S][S/64] bits.
__global__ __launch_bounds__(512) void attn_kernel(const unsigned short* __restrict__ Q,
                                                   const unsigned short* __restrict__ K,
                                                   const unsigned short* __restrict__ VT,
                                                   const unsigned long long* __restrict__ bm,
                                                   float* __restrict__ attn_out,
                                                   float* __restrict__ Ob) {
    __shared__ __align__(16) unsigned short pl[8][16][72]; // per-wave P tile (bf16), padded
    __shared__ float mlb[8][16][2];                        // per-wave (m,l) per row
    __shared__ float obuf[4][16][68];                      // O merge buffer (kh=1 -> kh=0)

    int lane = threadIdx.x & 63;
    int wave = threadIdx.x >> 6;
    int wgrp = wave & 3, kh = wave >> 2;
    int lrow = lane & 15, lgrp = lane >> 4;
    int bh = blockIdx.y;
    int b = bh >> 3, h = bh & 7;
    int qw = blockIdx.x * 64 + wgrp * 16;   // this group's 16 q rows
    int kt0 = kh * (NS / 2), kt1 = kt0 + NS / 2;

    const unsigned short* qrow = Q + ((size_t)bh * NS + qw + lrow) * NDK + lgrp * 8;
    bf16x8 aq0 = *(const bf16x8*)(qrow);
    bf16x8 aq1 = *(const bf16x8*)(qrow + 32);

    const unsigned short* kbase = K + (size_t)bh * NS * NDK;
    const unsigned short* vbase = VT + (size_t)bh * NDK * NS;
    const unsigned long long* bmb = bm + (size_t)b * NS * (NS / 64);
    int bmoff[4];
#pragma unroll
    for (int j = 0; j < 4; j++) bmoff[j] = (qw + lgrp * 4 + j) * (NS / 64);

    float mrun[4] = {NEGINF, NEGINF, NEGINF, NEGINF};
    float lrun[4] = {0.f, 0.f, 0.f, 0.f};

    // -------- sweep 1: running row max + sum of exp over this K-half --------
    for (int kt = kt0; kt < kt1; kt += 64) {
        f32x4 sc[4] = {{0.f,0.f,0.f,0.f},{0.f,0.f,0.f,0.f},{0.f,0.f,0.f,0.f},{0.f,0.f,0.f,0.f}};
#pragma unroll
        for (int n = 0; n < 4; n++) {
            const unsigned short* krow = kbase + (size_t)(kt + n * 16 + lrow) * NDK + lgrp * 8;
            bf16x8 b0 = *(const bf16x8*)(krow);
            bf16x8 b1 = *(const bf16x8*)(krow + 32);
            sc[n] = __builtin_amdgcn_mfma_f32_16x16x32_bf16(aq0, b0, sc[n], 0, 0, 0);
            sc[n] = __builtin_amdgcn_mfma_f32_16x16x32_bf16(aq1, b1, sc[n], 0, 0, 0);
        }
        unsigned long long w[4];
#pragma unroll
        for (int j = 0; j < 4; j++) w[j] = bmb[bmoff[j] + (kt >> 6)];
#pragma unroll
        for (int j = 0; j < 4; j++) {
            float s0 = ((w[j] >> (0 * 16 + lrow)) & 1) ? NEGINF : sc[0][j];
            float s1 = ((w[j] >> (1 * 16 + lrow)) & 1) ? NEGINF : sc[1][j];
            float s2 = ((w[j] >> (2 * 16 + lrow)) & 1) ? NEGINF : sc[2][j];
            float s3 = ((w[j] >> (3 * 16 + lrow)) & 1) ? NEGINF : sc[3][j];
            float tm = fmaxf(fmaxf(s0, s1), fmaxf(s2, s3));
            tm = fmaxf(tm, __shfl_xor(tm, 1));
            tm = fmaxf(tm, __shfl_xor(tm, 2));
            tm = fmaxf(tm, __shfl_xor(tm, 4));
            tm = fmaxf(tm, __shfl_xor(tm, 8));
            float mnew = fmaxf(mrun[j], tm);
            float su = __expf(s0 - mnew) + __expf(s1 - mnew)
                     + __expf(s2 - mnew) + __expf(s3 - mnew);
            su += __shfl_xor(su, 1);
            su += __shfl_xor(su, 2);
            su += __shfl_xor(su, 4);
            su += __shfl_xor(su, 8);
            lrun[j] = lrun[j] * __expf(mrun[j] - mnew) + su;
            mrun[j] = mnew;
        }
    }

    // -------- merge (m,l) across the two K-halves --------
    if (lrow == 0) {
#pragma unroll
        for (int j = 0; j < 4; j++) {
            mlb[wave][lgrp * 4 + j][0] = mrun[j];
            mlb[wave][lgrp * 4 + j][1] = lrun[j];
        }
    }
    __syncthreads();
    float mfin[4], invl[4];
#pragma unroll
    for (int j = 0; j < 4; j++) {
        int row = lgrp * 4 + j;
        float m0 = mlb[wgrp][row][0],     l0 = mlb[wgrp][row][1];
        float m1 = mlb[4 + wgrp][row][0], l1 = mlb[4 + wgrp][row][1];
        float m = fmaxf(m0, m1);
        float l = l0 * __expf(m0 - m) + l1 * __expf(m1 - m);
        mfin[j] = m;
        invl[j] = 1.f / l;
    }

    // -------- sweep 2: recompute scores, write attn, accumulate partial O --------
    f32x4 accO[4] = {{0.f,0.f,0.f,0.f},{0.f,0.f,0.f,0.f},{0.f,0.f,0.f,0.f},{0.f,0.f,0.f,0.f}};
    float* aout = attn_out + (size_t)bh * NS * NS;
    for (int kt = kt0; kt < kt1; kt += 64) {
        f32x4 sc[4] = {{0.f,0.f,0.f,0.f},{0.f,0.f,0.f,0.f},{0.f,0.f,0.f,0.f},{0.f,0.f,0.f,0.f}};
#pragma unroll
        for (int n = 0; n < 4; n++) {
            const unsigned short* krow = kbase + (size_t)(kt + n * 16 + lrow) * NDK + lgrp * 8;
            bf16x8 b0 = *(const bf16x8*)(krow);
            bf16x8 b1 = *(const bf16x8*)(krow + 32);
            sc[n] = __builtin_amdgcn_mfma_f32_16x16x32_bf16(aq0, b0, sc[n], 0, 0, 0);
            sc[n] = __builtin_amdgcn_mfma_f32_16x16x32_bf16(aq1, b1, sc[n], 0, 0, 0);
        }
        unsigned long long w[4];
#pragma unroll
        for (int j = 0; j < 4; j++) w[j] = bmb[bmoff[j] + (kt >> 6)];
#pragma unroll
        for (int n = 0; n < 4; n++)
#pragma unroll
            for (int j = 0; j < 4; j++) {
                int qi = qw + lgrp * 4 + j;
                int ki = kt + n * 16 + lrow;
                float p = ((w[j] >> (n * 16 + lrow)) & 1) ? 0.f
                        : __expf(sc[n][j] - mfin[j]) * invl[j];
                __builtin_nontemporal_store(p, &aout[(size_t)qi * NS + ki]);
                pl[wave][lgrp * 4 + j][n * 16 + lrow] = f2bf(p);
            }
#pragma unroll
        for (int step = 0; step < 2; step++) {
            bf16x8 ap = *(const bf16x8*)&pl[wave][lrow][step * 32 + lgrp * 8];
#pragma unroll
            for (int n = 0; n < 4; n++) {
                const unsigned short* vrow = vbase + (size_t)(n * 16 + lrow) * NS + kt + step * 32 + lgrp * 8;
                bf16x8 bv = *(const bf16x8*)vrow;
                accO[n] = __builtin_amdgcn_mfma_f32_16x16x32_bf16(ap, bv, accO[n], 0, 0, 0);
            }
        }
    }

    // -------- merge partial O across K-halves, write Ob --------
    if (kh == 1) {
#pragma unroll
        for (int n = 0; n < 4; n++)
#pragma unroll
            for (int j = 0; j < 4; j++)
                obuf[wgrp][lgrp * 4 + j][n * 16 + lrow] = accO[n][j];
    }
    __syncthreads();
    if (kh == 0) {
#pragma unroll
        for (int n = 0; n < 4; n++)
#pragma unroll
            for (int j = 0; j < 4; j++) {
                int qi = qw + lgrp * 4 + j;
                float o = accO[n][j] + obuf[wgrp][lgrp * 4 + j][n * 16 + lrow];
                Ob[((size_t)b * NS + qi) * ND + h * NDK + n * 16 + lrow] = o;
            }
    }
}

// ---------------- residual + LayerNorm (OpenNMT: unbiased std, eps on std) ----------------
__global__ __launch_bounds__(256) void ln_kernel(const float* __restrict__ Ob,
                                                 const float* __restrict__ query,
                                                 const float* __restrict__ a2,
                                                 const float* __restrict__ b2,
                                                 float* __restrict__ out) {
    int row = blockIdx.x * 4 + (threadIdx.x >> 6);
    int lane = threadIdx.x & 63;
    const float4* orow = (const float4*)(Ob + (size_t)row * ND);
    const float4* qrow = (const float4*)(query + (size_t)row * ND);
    float4 v[2];
    float sum = 0.f;
#pragma unroll
    for (int t = 0; t < 2; t++) {
        float4 o = orow[lane + t * 64];
        float4 q = qrow[lane + t * 64];
        v[t].x = o.x + q.x; v[t].y = o.y + q.y; v[t].z = o.z + q.z; v[t].w = o.w + q.w;
        sum += v[t].x + v[t].y + v[t].z + v[t].w;
    }
#pragma unroll
    for (int s = 1; s < 64; s <<= 1) sum += __shfl_xor(sum, s);
    float mu = sum * (1.f / ND);
    float sq = 0.f;
#pragma unroll
    for (int t = 0; t < 2; t++) {
        float dx = v[t].x - mu, dy = v[t].y - mu, dz = v[t].z - mu, dw = v[t].w - mu;
        sq += dx * dx + dy * dy + dz * dz + dw * dw;
    }
#pragma unroll
    for (int s = 1; s < 64; s <<= 1) sq += __shfl_xor(sq, s);
    float var = sq * (1.f / (ND - 1));
    float inv = 1.f / (sqrtf(var) + 1e-6f);
    float4* orow_out = (float4*)(out + (size_t)row * ND);
#pragma unroll
    for (int t = 0; t < 2; t++) {
        float4 g = ((const float4*)a2)[lane + t * 64];
        float4 bb = ((const float4*)b2)[lane + t * 64];
        float4 r;
        r.x = g.x * (v[t].x - mu) * inv + bb.x;
        r.y = g.y * (v[t].y - mu) * inv + bb.y;
        r.z = g.z * (v[t].z - mu) * inv + bb.z;
        r.w = g.w * (v[t].w - mu) * inv + bb.w;
        orow_out[lane + t * 64] = r;
    }
}

extern "C" void kernel_launch(void* const* d_in, const int* in_sizes, int n_in,
                              void* d_out, int out_size, void* d_ws, size_t ws_size,
                              hipStream_t stream) {
    const float* key   = (const float*)d_in[0];
    const float* value = (const float*)d_in[1];
    const float* query = (const float*)d_in[2];
    const int*   mask  = (const int*)d_in[3];
    const float* Wk = (const float*)d_in[4];
    const float* bk = (const float*)d_in[5];
    const float* Wv = (const float*)d_in[6];
    const float* bv = (const float*)d_in[7];
    const float* Wq = (const float*)d_in[8];
    const float* bq = (const float*)d_in[9];
    const float* a2 = (const float*)d_in[10];
    const float* b2 = (const float*)d_in[11];

    const size_t nX = (size_t)NB * NS * ND;   // 4,194,304
    const size_t nW = (size_t)ND * ND;        // 262,144
    const int    nBMw = NB * NS * NS / 64;    // 262,144 uint64 words

    unsigned short* xq  = (unsigned short*)d_ws;  // bf16 buffers
    unsigned short* xk  = xq + nX;
    unsigned short* xv  = xk + nX;
    unsigned short* wqb = xv + nX;
    unsigned short* wkb = wqb + nW;
    unsigned short* wvb = wkb + nW;
    unsigned short* Qw  = wvb + nW;               // [BH][S][dk]
    unsigned short* Kw  = Qw + nX;                // [BH][S][dk]
    unsigned short* VTw = Kw + nX;                // [BH][dk][S]
    float* Ow = (float*)(VTw + nX);               // [B][S][D] fp32
    unsigned long long* bmw = (unsigned long long*)(Ow + nX);  // bitmask, 2 MB

    bitmask_kernel<<<2048, 256, 0, stream>>>(mask, bmw, nBMw);

    cvt_bf16_kernel<<<(int)(nX / 4 / 256), 256, 0, stream>>>((const float4*)query, (ushort4*)xq, (int)(nX / 4));
    cvt_bf16_kernel<<<(int)(nX / 4 / 256), 256, 0, stream>>>((const float4*)key,   (ushort4*)xk, (int)(nX / 4));
    cvt_bf16_kernel<<<(int)(nX / 4 / 256), 256, 0, stream>>>((const float4*)value, (ushort4*)xv, (int)(nX / 4));
    cvt_bf16_kernel<<<(int)(nW / 4 / 256), 256, 0, stream>>>((const float4*)Wq, (ushort4*)wqb, (int)(nW / 4));
    cvt_bf16_kernel<<<(int)(nW / 4 / 256), 256, 0, stream>>>((const float4*)Wk, (ushort4*)wkb, (int)(nW / 4));
    cvt_bf16_kernel<<<(int)(nW / 4 / 256), 256, 0, stream>>>((const float4*)Wv, (ushort4*)wvb, (int)(nW / 4));

    dim3 pg(128, 8);
    proj_kernel<<<pg, 256, 0, stream>>>(xq, wqb, bq, Qw, 0.125f, 0);  // Q scaled by 1/sqrt(dk)
    proj_kernel<<<pg, 256, 0, stream>>>(xk, wkb, bk, Kw, 1.0f, 0);
    proj_kernel<<<pg, 256, 0, stream>>>(xv, wvb, bv, VTw, 1.0f, 1);

    float* attn_out = (float*)d_out + nX;  // res occupies first nX floats
    attn_kernel<<<dim3(32, 32), 512, 0, stream>>>(Qw, Kw, VTw, bmw, attn_out, Ow);

    ln_kernel<<<2048, 256, 0, stream>>>(Ow, query, a2, b2, (float*)d_out);
}